// Round 14
// baseline (126.887 us; speedup 1.0000x reference)
//
#include <hip/hip_runtime.h>
#include <cstdint>
#include <cstddef>

// Problem sizes (fixed by the reference)
#define MDIM 16384   // N_INPUT
#define CDIM 4096    // NUM_CENTERS
#define DDIM 256     // DIM
#define KDIM 512     // folded K elements; fp4 -> 256 bytes per row
#define KB   256     // row bytes (fp4)

typedef float f32x4  __attribute__((ext_vector_type(4)));
typedef int   i32x4v __attribute__((ext_vector_type(4)));
typedef int   i32x8v __attribute__((ext_vector_type(8)));

// e2m1 (OCP MXFP4) quantize, round-to-nearest: grid {0,.5,1,1.5,2,3,4,6}
__device__ __forceinline__ unsigned q4(float v) {
    unsigned s = (__builtin_bit_cast(unsigned, v) >> 31) << 3;
    float a = fabsf(v);
    unsigned c = (unsigned)(a >= 0.25f) + (a >= 0.75f) + (a >= 1.25f)
               + (a >= 1.75f) + (a >= 2.5f) + (a >= 3.5f) + (a >= 5.0f);
    return s | c;
}
__device__ __forceinline__ unsigned pack8(const float* v) {  // 8 vals -> 8 nibbles
    unsigned w = 0;
    #pragma unroll
    for (int i = 0; i < 8; ++i) w |= q4(v[i]) << (4 * i);
    return w;
}

// ---------------------------------------------------------------------------
// prep (fp4): A'[n] = [ x (256 fp4) | x^2/8 (256 fp4) ]       row = 256 B
//             B'[c] = [ -2*c*inv (256 fp4) | inv*8 (256 fp4) ]
//             constc[c] = sum_d c^2*inv (fp32).  Scales undone by MFMA E8M0.
// ---------------------------------------------------------------------------
__global__ __launch_bounds__(256) void prep(
    const float* __restrict__ x, const float* __restrict__ centers,
    const float* __restrict__ sigmas,
    unsigned char* __restrict__ Ap, unsigned char* __restrict__ Bp,
    float* __restrict__ constc, float* __restrict__ score) {
    int b = blockIdx.x, tid = threadIdx.x;
    if (b < 2048) {
        int idx8 = b * 256 + tid;                 // over MDIM*DDIM/8
        int n = idx8 >> 5, d8 = idx8 & 31;
        float v[8], v2[8];
        *(float4*)(v)     = ((const float4*)x)[idx8 * 2];
        *(float4*)(v + 4) = ((const float4*)x)[idx8 * 2 + 1];
        #pragma unroll
        for (int i = 0; i < 8; ++i) v2[i] = v[i] * v[i] * 0.125f;  // x^2/8
        *(unsigned*)(Ap + (size_t)n * KB + d8 * 4)       = pack8(v);
        *(unsigned*)(Ap + (size_t)n * KB + 128 + d8 * 4) = pack8(v2);
        if (idx8 < MDIM) score[idx8] = 0.0f;
    } else {
        int gid8 = (b - 2048) * 256 + tid;        // over CDIM*DDIM/8
        int c = gid8 >> 5, d8 = gid8 & 31;
        float cv[8], sv[8], cr[8], iv[8];
        *(float4*)(cv)     = ((const float4*)centers)[gid8 * 2];
        *(float4*)(cv + 4) = ((const float4*)centers)[gid8 * 2 + 1];
        *(float4*)(sv)     = ((const float4*)sigmas)[gid8 * 2];
        *(float4*)(sv + 4) = ((const float4*)sigmas)[gid8 * 2 + 1];
        float t = 0.0f;
        #pragma unroll
        for (int i = 0; i < 8; ++i) {
            float inv = 1.0f / (2.0f * sv[i] * sv[i]);
            cr[i] = -2.0f * cv[i] * inv;
            iv[i] = inv * 8.0f;                   // inv*8 (undone by 2^-3)
            t += cv[i] * cv[i] * inv;
        }
        *(unsigned*)(Bp + (size_t)c * KB + d8 * 4)       = pack8(cr);
        *(unsigned*)(Bp + (size_t)c * KB + 128 + d8 * 4) = pack8(iv);
        #pragma unroll
        for (int m = 16; m; m >>= 1) t += __shfl_xor(t, m, 64);  // 32-lane groups
        if ((tid & 31) == 0) constc[c] = t;
    }
}

// ---------------------------------------------------------------------------
// Fused MX-fp4 GEMM + exp + weighted C-reduction.
// d2 = A' B'^T + constc ; score[m] += sum_n exp(-d2[m][n]) * w[n]
// R13 = R12 with 2x2 wave tiling: wave (wm,wn) owns 64M x 64N -> per
// window 4 A-frags + 4 B-frags feed 16 MFMAs (R12: 2+8 for 16) -> block
// LDS reads 160->128 KB (the top pipe in the cycle audit), 16 independent
// acc chains. acc[4][4]=64 regs (same pressure), launch_bounds(256,4).
// Everything else identical: 32 KB LDS, XOR swizzle g^(r&7) (2-way alias,
// free), BK=256-elem rounds, 16x16x128 fp4, per-round E8M0 scales,
// epilogue constants loaded after the K-loop.
// ---------------------------------------------------------------------------
__global__ __launch_bounds__(256, 4) void gemm_fused(
    const unsigned char* __restrict__ A, const unsigned char* __restrict__ B,
    const float* __restrict__ constc, const float* __restrict__ w,
    float* __restrict__ score) {

    __shared__ unsigned char As[128 * 128];   // 16 KB
    __shared__ unsigned char Bs[128 * 128];   // 16 KB

    const int tid  = threadIdx.x;
    const int wave = tid >> 6;
    const int lane = tid & 63;
    const int quad = lane >> 4;      // 0..3
    const int l16  = lane & 15;

    const int bm = blockIdx.y;       // 0..127  (M blocks of 128)
    const int bn = blockIdx.x;       // 0..31   (C blocks of 128)

    const int wave_m = (wave & 1) * 64;   // wave's 64 M-rows
    const int wave_n = (wave >> 1) * 64;  // wave's 64 N-cols

    f32x4 acc[4][4] = {};

    // staging: one global_load_lds(16B)/lane stages 1024 B = 8 rows x 128 B.
    // lane -> row (lane>>3), slot (lane&7); fetch XOR-swizzled global chunk.
    const int st_row = lane >> 3;                     // 0..7
    const int st_k   = ((lane & 7) ^ st_row) * 16;    // swizzled global byte off

    const unsigned char* Abase = A + (size_t)(bm * 128) * KB;
    const unsigned char* Bbase = B + (size_t)(bn * 128) * KB;

    const int rsw = l16 & 7;

    #pragma unroll
    for (int k0 = 0; k0 < 2; ++k0) {              // 2 rounds of 128 B (=256 elems)
        const int sA = k0 ? 0x82828282 : 0x7F7F7F7F;   // 2^3 : 2^0
        const int sB = k0 ? 0x7C7C7C7C : 0x7F7F7F7F;   // 2^-3 : 2^0
        #pragma unroll
        for (int c = 0; c < 4; ++c) {             // A: 16 slabs of 8 rows
            int slab = wave * 4 + c;              // 0..15
            const unsigned char* ga = Abase + (size_t)(slab * 8 + st_row) * KB + k0 * 128 + st_k;
            __builtin_amdgcn_global_load_lds(
                (const __attribute__((address_space(1))) void*)ga,
                (__attribute__((address_space(3))) void*)(As + slab * 1024), 16, 0, 0);
        }
        #pragma unroll
        for (int c = 0; c < 4; ++c) {             // B: 16 slabs of 8 rows
            int slab = wave * 4 + c;              // 0..15
            const unsigned char* gb = Bbase + (size_t)(slab * 8 + st_row) * KB + k0 * 128 + st_k;
            __builtin_amdgcn_global_load_lds(
                (const __attribute__((address_space(1))) void*)gb,
                (__attribute__((address_space(3))) void*)(Bs + slab * 1024), 16, 0, 0);
        }
        __syncthreads();

        #pragma unroll
        for (int kh = 0; kh < 2; ++kh) {          // two K=128 MFMA windows
            const int sl = ((kh * 4 + quad) ^ rsw) * 16;
            i32x8v af[4];
            #pragma unroll
            for (int i = 0; i < 4; ++i) {
                i32x4v lo = *(const i32x4v*)(As + (wave_m + i * 16 + l16) * 128 + sl);
                af[i] = __builtin_shufflevector(lo, lo, 0, 1, 2, 3, -1, -1, -1, -1);
            }
            #pragma unroll
            for (int j = 0; j < 4; ++j) {
                i32x4v lo = *(const i32x4v*)(Bs + (wave_n + j * 16 + l16) * 128 + sl);
                i32x8v bf = __builtin_shufflevector(lo, lo, 0, 1, 2, 3, -1, -1, -1, -1);
                #pragma unroll
                for (int i = 0; i < 4; ++i)
                    acc[i][j] = __builtin_amdgcn_mfma_scale_f32_16x16x128_f8f6f4(
                        af[i], bf, acc[i][j],
                        4 /*cbsz: fp4 e2m1*/, 4 /*blgp: fp4 e2m1*/,
                        0, sA, 0, sB);
            }
        }
        __syncthreads();
    }

    // Epilogue (constants loaded here, once per block — keeps K-loop regs low).
    // C/D layout (16x16 shapes): col = l16 (=n), row = quad*4 + reg (=m).
    const float NEG_LOG2E = -1.4426950408889634f;
    float rowsum[4][4];
    #pragma unroll
    for (int i = 0; i < 4; ++i)
        #pragma unroll
        for (int r = 0; r < 4; ++r) rowsum[i][r] = 0.0f;

    #pragma unroll
    for (int j = 0; j < 4; ++j) {
        int ng = bn * 128 + wave_n + j * 16 + l16;
        float wj  = w[ng];
        float cjl = NEG_LOG2E * constc[ng];
        #pragma unroll
        for (int i = 0; i < 4; ++i)
            #pragma unroll
            for (int r = 0; r < 4; ++r)
                rowsum[i][r] += exp2f(fmaf(acc[i][j][r], NEG_LOG2E, cjl)) * wj;
    }

    #pragma unroll
    for (int mask = 1; mask < 16; mask <<= 1)
        #pragma unroll
        for (int i = 0; i < 4; ++i)
            #pragma unroll
            for (int r = 0; r < 4; ++r)
                rowsum[i][r] += __shfl_xor(rowsum[i][r], mask, 64);

    if (l16 == 0) {
        #pragma unroll
        for (int i = 0; i < 4; ++i)
            #pragma unroll
            for (int r = 0; r < 4; ++r) {
                int mg = bm * 128 + wave_m + i * 16 + quad * 4 + r;
                atomicAdd(&score[mg], rowsum[i][r]);
            }
    }
}

// ---------------------------------------------------------------------------
// finalize: out[n] = sigmoid(score[n] + b)
// ---------------------------------------------------------------------------
__global__ void finalize(const float* __restrict__ score,
                         const float* __restrict__ b,
                         float* __restrict__ out) {
    int n = blockIdx.x * 256 + threadIdx.x;
    if (n < MDIM) {
        float s = score[n] + b[0];
        out[n] = 1.0f / (1.0f + exp2f(-1.4426950408889634f * s));
    }
}

extern "C" void kernel_launch(void* const* d_in, const int* in_sizes, int n_in,
                              void* d_out, int out_size, void* d_ws, size_t ws_size,
                              hipStream_t stream) {
    const float* x       = (const float*)d_in[0];
    const float* centers = (const float*)d_in[1];
    const float* sigmas  = (const float*)d_in[2];
    const float* w_lin   = (const float*)d_in[3];
    const float* b_lin   = (const float*)d_in[4];
    float* out = (float*)d_out;

    char* ws = (char*)d_ws;
    unsigned char* Ap = (unsigned char*)ws;                       // 4 MB
    unsigned char* Bp = (unsigned char*)(ws + (size_t)MDIM * KB); // 1 MB
    float* cc    = (float*)(ws + (size_t)MDIM * KB + (size_t)CDIM * KB); // 16 KB
    float* score = (float*)((char*)cc + CDIM * sizeof(float));    // 64 KB

    prep<<<dim3(2048 + 512), dim3(256), 0, stream>>>(
        x, centers, sigmas, Ap, Bp, cc, score);
    gemm_fused<<<dim3(CDIM / 128, MDIM / 128), dim3(256), 0, stream>>>(
        Ap, Bp, cc, w_lin, score);
    finalize<<<dim3((MDIM + 255) / 256), dim3(256), 0, stream>>>(score, b_lin, out);
}

// Round 15
// 120.188 us; speedup vs baseline: 1.0557x; 1.0557x over previous
//
#include <hip/hip_runtime.h>
#include <cstdint>
#include <cstddef>

// Problem sizes (fixed by the reference)
#define MDIM 16384   // N_INPUT
#define CDIM 4096    // NUM_CENTERS
#define DDIM 256     // DIM
#define KDIM 512     // folded K elements; fp4 -> 256 bytes per row
#define KB   256     // row bytes (fp4)

typedef float f32x4  __attribute__((ext_vector_type(4)));
typedef int   i32x4v __attribute__((ext_vector_type(4)));
typedef int   i32x8v __attribute__((ext_vector_type(8)));

// e2m1 (OCP MXFP4) quantize, round-to-nearest: grid {0,.5,1,1.5,2,3,4,6}
__device__ __forceinline__ unsigned q4(float v) {
    unsigned s = (__builtin_bit_cast(unsigned, v) >> 31) << 3;
    float a = fabsf(v);
    unsigned c = (unsigned)(a >= 0.25f) + (a >= 0.75f) + (a >= 1.25f)
               + (a >= 1.75f) + (a >= 2.5f) + (a >= 3.5f) + (a >= 5.0f);
    return s | c;
}
__device__ __forceinline__ unsigned pack8(const float* v) {  // 8 vals -> 8 nibbles
    unsigned w = 0;
    #pragma unroll
    for (int i = 0; i < 8; ++i) w |= q4(v[i]) << (4 * i);
    return w;
}

// ---------------------------------------------------------------------------
// prep (fp4): A'[n] = [ x (256 fp4) | x^2/8 (256 fp4) ]       row = 256 B
//             B'[c] = [ -2*c*inv (256 fp4) | inv*8 (256 fp4) ]
//             constc[c] = sum_d c^2*inv (fp32).  Scales undone by MFMA E8M0.
// ---------------------------------------------------------------------------
__global__ __launch_bounds__(256) void prep(
    const float* __restrict__ x, const float* __restrict__ centers,
    const float* __restrict__ sigmas,
    unsigned char* __restrict__ Ap, unsigned char* __restrict__ Bp,
    float* __restrict__ constc, float* __restrict__ score) {
    int b = blockIdx.x, tid = threadIdx.x;
    if (b < 2048) {
        int idx8 = b * 256 + tid;                 // over MDIM*DDIM/8
        int n = idx8 >> 5, d8 = idx8 & 31;
        float v[8], v2[8];
        *(float4*)(v)     = ((const float4*)x)[idx8 * 2];
        *(float4*)(v + 4) = ((const float4*)x)[idx8 * 2 + 1];
        #pragma unroll
        for (int i = 0; i < 8; ++i) v2[i] = v[i] * v[i] * 0.125f;  // x^2/8
        *(unsigned*)(Ap + (size_t)n * KB + d8 * 4)       = pack8(v);
        *(unsigned*)(Ap + (size_t)n * KB + 128 + d8 * 4) = pack8(v2);
        if (idx8 < MDIM) score[idx8] = 0.0f;
    } else {
        int gid8 = (b - 2048) * 256 + tid;        // over CDIM*DDIM/8
        int c = gid8 >> 5, d8 = gid8 & 31;
        float cv[8], sv[8], cr[8], iv[8];
        *(float4*)(cv)     = ((const float4*)centers)[gid8 * 2];
        *(float4*)(cv + 4) = ((const float4*)centers)[gid8 * 2 + 1];
        *(float4*)(sv)     = ((const float4*)sigmas)[gid8 * 2];
        *(float4*)(sv + 4) = ((const float4*)sigmas)[gid8 * 2 + 1];
        float t = 0.0f;
        #pragma unroll
        for (int i = 0; i < 8; ++i) {
            float inv = 1.0f / (2.0f * sv[i] * sv[i]);
            cr[i] = -2.0f * cv[i] * inv;
            iv[i] = inv * 8.0f;                   // inv*8 (undone by 2^-3)
            t += cv[i] * cv[i] * inv;
        }
        *(unsigned*)(Bp + (size_t)c * KB + d8 * 4)       = pack8(cr);
        *(unsigned*)(Bp + (size_t)c * KB + 128 + d8 * 4) = pack8(iv);
        #pragma unroll
        for (int m = 16; m; m >>= 1) t += __shfl_xor(t, m, 64);  // 32-lane groups
        if ((tid & 31) == 0) constc[c] = t;
    }
}

// ---------------------------------------------------------------------------
// Fused MX-fp4 GEMM + exp + weighted C-reduction, B-resident 2-bm blocks.
// d2 = A' B'^T + constc ; score[m] += sum_n exp(-d2[m][n]) * w[n]
// R14: grid 32x64; each block owns bn and TWO bm tiles. Bs (both K-rounds,
// 32 KB) staged once and LDS-resident; As (16 KB) restaged per round.
// LDS 48 KB -> 3 blocks/CU, (256,3). Per 2-bm: staging 96 KB vs R12's
// 128 KB; one prologue; t1's A-stage issued before t0's epilogue so its
// latency hides under epilogue VALU. Wave layout/compute = R12 exactly:
// wave = 32M x 128N, acc[2][8], 16x16x128 fp4, XOR swizzle g^(r&7),
// per-round E8M0 scales (r0: 1*1, r1: 2^3 * 2^-3).
// ---------------------------------------------------------------------------
__global__ __launch_bounds__(256, 3) void gemm_fused(
    const unsigned char* __restrict__ A, const unsigned char* __restrict__ B,
    const float* __restrict__ constc, const float* __restrict__ w,
    float* __restrict__ score) {

    __shared__ unsigned char Bs[2 * 128 * 128];   // 32 KB (both K-rounds)
    __shared__ unsigned char As[128 * 128];       // 16 KB (one K-round)

    const int tid  = threadIdx.x;
    const int wave = tid >> 6;
    const int lane = tid & 63;
    const int quad = lane >> 4;      // 0..3
    const int l16  = lane & 15;

    const int bn  = blockIdx.x;      // 0..31  (C blocks of 128)
    const int bm0 = blockIdx.y * 2;  // 0..126 (first of two M blocks of 128)

    const int wave_m = wave * 32;    // wave's 32 M-rows

    const float NEG_LOG2E = -1.4426950408889634f;

    // staging: one global_load_lds(16B)/lane stages 1024 B = 8 rows x 128 B.
    const int st_row = lane >> 3;                     // 0..7
    const int st_k   = ((lane & 7) ^ st_row) * 16;    // swizzled global byte off

    const unsigned char* Bbase = B + (size_t)(bn * 128) * KB;
    const unsigned char* A0    = A + (size_t)(bm0 * 128) * KB;
    const unsigned char* A1    = A0 + (size_t)128 * KB;

    const int rsw = l16 & 7;

    f32x4 acc[2][8] = {};

    #define STAGE_A(abase, k0)                                                     \
        {                                                                          \
            _Pragma("unroll")                                                      \
            for (int c = 0; c < 4; ++c) {                                          \
                int slab = wave * 4 + c;                                           \
                const unsigned char* ga =                                          \
                    (abase) + (size_t)(slab * 8 + st_row) * KB + (k0) * 128 + st_k;\
                __builtin_amdgcn_global_load_lds(                                  \
                    (const __attribute__((address_space(1))) void*)ga,             \
                    (__attribute__((address_space(3))) void*)(As + slab * 1024),   \
                    16, 0, 0);                                                     \
            }                                                                      \
        }

    #define COMPUTE(k0)                                                            \
        {                                                                          \
            const int sA = (k0) ? 0x82828282 : 0x7F7F7F7F;                         \
            const int sB = (k0) ? 0x7C7C7C7C : 0x7F7F7F7F;                         \
            const unsigned char* bs = Bs + (k0) * 16384;                           \
            _Pragma("unroll")                                                      \
            for (int kh = 0; kh < 2; ++kh) {                                       \
                const int sl = ((kh * 4 + quad) ^ rsw) * 16;                       \
                i32x8v af[2];                                                      \
                _Pragma("unroll")                                                  \
                for (int i = 0; i < 2; ++i) {                                      \
                    i32x4v lo = *(const i32x4v*)(As + (wave_m + i * 16 + l16) * 128 + sl); \
                    af[i] = __builtin_shufflevector(lo, lo, 0, 1, 2, 3, -1, -1, -1, -1);   \
                }                                                                  \
                _Pragma("unroll")                                                  \
                for (int j = 0; j < 8; ++j) {                                      \
                    i32x4v lo = *(const i32x4v*)(bs + (j * 16 + l16) * 128 + sl);  \
                    i32x8v bf = __builtin_shufflevector(lo, lo, 0, 1, 2, 3, -1, -1, -1, -1); \
                    _Pragma("unroll")                                              \
                    for (int i = 0; i < 2; ++i)                                    \
                        acc[i][j] = __builtin_amdgcn_mfma_scale_f32_16x16x128_f8f6f4( \
                            af[i], bf, acc[i][j], 4, 4, 0, sA, 0, sB);             \
                }                                                                  \
            }                                                                      \
        }

    #define EPILOGUE(bmrow)                                                        \
        {                                                                          \
            float rowsum[2][4];                                                    \
            _Pragma("unroll")                                                      \
            for (int i = 0; i < 2; ++i)                                            \
                _Pragma("unroll")                                                  \
                for (int r = 0; r < 4; ++r) rowsum[i][r] = 0.0f;                   \
            _Pragma("unroll")                                                      \
            for (int j = 0; j < 8; ++j) {                                          \
                int ng = bn * 128 + j * 16 + l16;                                  \
                float wj  = w[ng];                                                 \
                float cjl = NEG_LOG2E * constc[ng];                                \
                _Pragma("unroll")                                                  \
                for (int i = 0; i < 2; ++i)                                        \
                    _Pragma("unroll")                                              \
                    for (int r = 0; r < 4; ++r)                                    \
                        rowsum[i][r] += exp2f(fmaf(acc[i][j][r], NEG_LOG2E, cjl)) * wj; \
            }                                                                      \
            _Pragma("unroll")                                                      \
            for (int mask = 1; mask < 16; mask <<= 1)                              \
                _Pragma("unroll")                                                  \
                for (int i = 0; i < 2; ++i)                                        \
                    _Pragma("unroll")                                              \
                    for (int r = 0; r < 4; ++r)                                    \
                        rowsum[i][r] += __shfl_xor(rowsum[i][r], mask, 64);        \
            if (l16 == 0) {                                                        \
                _Pragma("unroll")                                                  \
                for (int i = 0; i < 2; ++i)                                        \
                    _Pragma("unroll")                                              \
                    for (int r = 0; r < 4; ++r) {                                  \
                        int mg = (bmrow) * 128 + wave_m + i * 16 + quad * 4 + r;   \
                        atomicAdd(&score[mg], rowsum[i][r]);                       \
                    }                                                              \
            }                                                                      \
            _Pragma("unroll")                                                      \
            for (int i = 0; i < 2; ++i)                                            \
                _Pragma("unroll")                                                  \
                for (int j = 0; j < 8; ++j) acc[i][j] = (f32x4){0,0,0,0};          \
        }

    // prologue: stage B (both rounds) + A(t0, r0)
    #pragma unroll
    for (int k0 = 0; k0 < 2; ++k0) {
        #pragma unroll
        for (int c = 0; c < 4; ++c) {
            int slab = wave * 4 + c;
            const unsigned char* gb = Bbase + (size_t)(slab * 8 + st_row) * KB + k0 * 128 + st_k;
            __builtin_amdgcn_global_load_lds(
                (const __attribute__((address_space(1))) void*)gb,
                (__attribute__((address_space(3))) void*)(Bs + k0 * 16384 + slab * 1024),
                16, 0, 0);
        }
    }
    STAGE_A(A0, 0);
    __syncthreads();

    COMPUTE(0);                 // t0, round 0
    __syncthreads();
    STAGE_A(A0, 1);
    __syncthreads();
    COMPUTE(1);                 // t0, round 1
    __syncthreads();
    STAGE_A(A1, 0);             // issue t1's first A-stage...
    EPILOGUE(bm0);              // ...then hide it under t0's epilogue
    __syncthreads();
    COMPUTE(0);                 // t1, round 0
    __syncthreads();
    STAGE_A(A1, 1);
    __syncthreads();
    COMPUTE(1);                 // t1, round 1
    EPILOGUE(bm0 + 1);

    #undef STAGE_A
    #undef COMPUTE
    #undef EPILOGUE
}

// ---------------------------------------------------------------------------
// finalize: out[n] = sigmoid(score[n] + b)
// ---------------------------------------------------------------------------
__global__ void finalize(const float* __restrict__ score,
                         const float* __restrict__ b,
                         float* __restrict__ out) {
    int n = blockIdx.x * 256 + threadIdx.x;
    if (n < MDIM) {
        float s = score[n] + b[0];
        out[n] = 1.0f / (1.0f + exp2f(-1.4426950408889634f * s));
    }
}

extern "C" void kernel_launch(void* const* d_in, const int* in_sizes, int n_in,
                              void* d_out, int out_size, void* d_ws, size_t ws_size,
                              hipStream_t stream) {
    const float* x       = (const float*)d_in[0];
    const float* centers = (const float*)d_in[1];
    const float* sigmas  = (const float*)d_in[2];
    const float* w_lin   = (const float*)d_in[3];
    const float* b_lin   = (const float*)d_in[4];
    float* out = (float*)d_out;

    char* ws = (char*)d_ws;
    unsigned char* Ap = (unsigned char*)ws;                       // 4 MB
    unsigned char* Bp = (unsigned char*)(ws + (size_t)MDIM * KB); // 1 MB
    float* cc    = (float*)(ws + (size_t)MDIM * KB + (size_t)CDIM * KB); // 16 KB
    float* score = (float*)((char*)cc + CDIM * sizeof(float));    // 64 KB

    prep<<<dim3(2048 + 512), dim3(256), 0, stream>>>(
        x, centers, sigmas, Ap, Bp, cc, score);
    gemm_fused<<<dim3(CDIM / 128, MDIM / 256), dim3(256), 0, stream>>>(
        Ap, Bp, cc, w_lin, score);
    finalize<<<dim3((MDIM + 255) / 256), dim3(256), 0, stream>>>(score, b_lin, out);
}

// Round 16
// 115.868 us; speedup vs baseline: 1.0951x; 1.0373x over previous
//
#include <hip/hip_runtime.h>
#include <cstdint>
#include <cstddef>

// Problem sizes (fixed by the reference)
#define MDIM 16384   // N_INPUT
#define CDIM 4096    // NUM_CENTERS
#define DDIM 256     // DIM
#define KDIM 512     // folded K elements; fp4 -> 256 bytes per row
#define KB   256     // row bytes (fp4)

typedef float f32x4  __attribute__((ext_vector_type(4)));
typedef int   i32x4v __attribute__((ext_vector_type(4)));
typedef int   i32x8v __attribute__((ext_vector_type(8)));

// e2m1 (OCP MXFP4) quantize, round-to-nearest: grid {0,.5,1,1.5,2,3,4,6}
__device__ __forceinline__ unsigned q4(float v) {
    unsigned s = (__builtin_bit_cast(unsigned, v) >> 31) << 3;
    float a = fabsf(v);
    unsigned c = (unsigned)(a >= 0.25f) + (a >= 0.75f) + (a >= 1.25f)
               + (a >= 1.75f) + (a >= 2.5f) + (a >= 3.5f) + (a >= 5.0f);
    return s | c;
}
__device__ __forceinline__ unsigned pack8(const float* v) {  // 8 vals -> 8 nibbles
    unsigned w = 0;
    #pragma unroll
    for (int i = 0; i < 8; ++i) w |= q4(v[i]) << (4 * i);
    return w;
}

// ---------------------------------------------------------------------------
// prep (fp4): A'[n] = [ x (256 fp4) | x^2/8 (256 fp4) ]       row = 256 B
//             B'[c] = [ -2*c*inv (256 fp4) | inv*8 (256 fp4) ]
//             constc[c] = sum_d c^2*inv (fp32).  Scales undone by MFMA E8M0.
// ---------------------------------------------------------------------------
__global__ __launch_bounds__(256) void prep(
    const float* __restrict__ x, const float* __restrict__ centers,
    const float* __restrict__ sigmas,
    unsigned char* __restrict__ Ap, unsigned char* __restrict__ Bp,
    float* __restrict__ constc, float* __restrict__ score) {
    int b = blockIdx.x, tid = threadIdx.x;
    if (b < 2048) {
        int idx8 = b * 256 + tid;                 // over MDIM*DDIM/8
        int n = idx8 >> 5, d8 = idx8 & 31;
        float v[8], v2[8];
        *(float4*)(v)     = ((const float4*)x)[idx8 * 2];
        *(float4*)(v + 4) = ((const float4*)x)[idx8 * 2 + 1];
        #pragma unroll
        for (int i = 0; i < 8; ++i) v2[i] = v[i] * v[i] * 0.125f;  // x^2/8
        *(unsigned*)(Ap + (size_t)n * KB + d8 * 4)       = pack8(v);
        *(unsigned*)(Ap + (size_t)n * KB + 128 + d8 * 4) = pack8(v2);
        if (idx8 < MDIM) score[idx8] = 0.0f;
    } else {
        int gid8 = (b - 2048) * 256 + tid;        // over CDIM*DDIM/8
        int c = gid8 >> 5, d8 = gid8 & 31;
        float cv[8], sv[8], cr[8], iv[8];
        *(float4*)(cv)     = ((const float4*)centers)[gid8 * 2];
        *(float4*)(cv + 4) = ((const float4*)centers)[gid8 * 2 + 1];
        *(float4*)(sv)     = ((const float4*)sigmas)[gid8 * 2];
        *(float4*)(sv + 4) = ((const float4*)sigmas)[gid8 * 2 + 1];
        float t = 0.0f;
        #pragma unroll
        for (int i = 0; i < 8; ++i) {
            float inv = 1.0f / (2.0f * sv[i] * sv[i]);
            cr[i] = -2.0f * cv[i] * inv;
            iv[i] = inv * 8.0f;                   // inv*8 (undone by 2^-3)
            t += cv[i] * cv[i] * inv;
        }
        *(unsigned*)(Bp + (size_t)c * KB + d8 * 4)       = pack8(cr);
        *(unsigned*)(Bp + (size_t)c * KB + 128 + d8 * 4) = pack8(iv);
        #pragma unroll
        for (int m = 16; m; m >>= 1) t += __shfl_xor(t, m, 64);  // 32-lane groups
        if ((tid & 31) == 0) constc[c] = t;
    }
}

// ---------------------------------------------------------------------------
// Fused MX-fp4 GEMM + exp + weighted C-reduction.  (R12 — best measured.)
// d2 = A' B'^T + constc ; score[m] += sum_n exp(-d2[m][n]) * w[n]
// 128x128 tile, wave = 32M x 128N, acc[2][8], 32 KB LDS, XOR swizzle
// g^(r&7) (0 conflicts), BK=256-elem rounds, 16x16x128 fp4 MFMA,
// per-round E8M0 scales (r0: 1*1, r1: 2^3 * 2^-3), launch_bounds(256,4)
// with epilogue constants loaded after the K-loop (K-loop live ~110 regs).
// Session plateau note: dbuf (R9), 32x32 shape (R11), 2x2 wave tiling
// (R13), B-resident multi-bm (R14) all regressed or were neutral — the
// stage->barrier->compute chain is the structural limit at HIP level.
// ---------------------------------------------------------------------------
__global__ __launch_bounds__(256, 4) void gemm_fused(
    const unsigned char* __restrict__ A, const unsigned char* __restrict__ B,
    const float* __restrict__ constc, const float* __restrict__ w,
    float* __restrict__ score) {

    __shared__ unsigned char As[128 * 128];   // 16 KB
    __shared__ unsigned char Bs[128 * 128];   // 16 KB

    const int tid  = threadIdx.x;
    const int wave = tid >> 6;
    const int lane = tid & 63;
    const int quad = lane >> 4;      // 0..3
    const int l16  = lane & 15;

    const int bm = blockIdx.y;       // 0..127  (M blocks of 128)
    const int bn = blockIdx.x;       // 0..31   (C blocks of 128)

    const int wave_m = wave * 32;    // wave's 32 M-rows

    f32x4 acc[2][8] = {};

    // staging: one global_load_lds(16B)/lane stages 1024 B = 8 rows x 128 B.
    // lane -> row (lane>>3), slot (lane&7); fetch XOR-swizzled global chunk.
    const int st_row = lane >> 3;                     // 0..7
    const int st_k   = ((lane & 7) ^ st_row) * 16;    // swizzled global byte off

    const unsigned char* Abase = A + (size_t)(bm * 128) * KB;
    const unsigned char* Bbase = B + (size_t)(bn * 128) * KB;

    const int rsw = l16 & 7;

    #pragma unroll
    for (int k0 = 0; k0 < 2; ++k0) {              // 2 rounds of 128 B (=256 elems)
        const int sA = k0 ? 0x82828282 : 0x7F7F7F7F;   // 2^3 : 2^0
        const int sB = k0 ? 0x7C7C7C7C : 0x7F7F7F7F;   // 2^-3 : 2^0
        #pragma unroll
        for (int c = 0; c < 4; ++c) {             // A: 16 slabs of 8 rows
            int slab = wave * 4 + c;              // 0..15
            const unsigned char* ga = Abase + (size_t)(slab * 8 + st_row) * KB + k0 * 128 + st_k;
            __builtin_amdgcn_global_load_lds(
                (const __attribute__((address_space(1))) void*)ga,
                (__attribute__((address_space(3))) void*)(As + slab * 1024), 16, 0, 0);
        }
        #pragma unroll
        for (int c = 0; c < 4; ++c) {             // B: 16 slabs of 8 rows
            int slab = wave * 4 + c;              // 0..15
            const unsigned char* gb = Bbase + (size_t)(slab * 8 + st_row) * KB + k0 * 128 + st_k;
            __builtin_amdgcn_global_load_lds(
                (const __attribute__((address_space(1))) void*)gb,
                (__attribute__((address_space(3))) void*)(Bs + slab * 1024), 16, 0, 0);
        }
        __syncthreads();

        #pragma unroll
        for (int kh = 0; kh < 2; ++kh) {          // two K=128 MFMA windows
            const int sl = ((kh * 4 + quad) ^ rsw) * 16;
            i32x8v af[2];
            #pragma unroll
            for (int i = 0; i < 2; ++i) {
                i32x4v lo = *(const i32x4v*)(As + (wave_m + i * 16 + l16) * 128 + sl);
                af[i] = __builtin_shufflevector(lo, lo, 0, 1, 2, 3, -1, -1, -1, -1);
            }
            #pragma unroll
            for (int j = 0; j < 8; ++j) {
                i32x4v lo = *(const i32x4v*)(Bs + (j * 16 + l16) * 128 + sl);
                i32x8v bf = __builtin_shufflevector(lo, lo, 0, 1, 2, 3, -1, -1, -1, -1);
                #pragma unroll
                for (int i = 0; i < 2; ++i)
                    acc[i][j] = __builtin_amdgcn_mfma_scale_f32_16x16x128_f8f6f4(
                        af[i], bf, acc[i][j],
                        4 /*cbsz: fp4 e2m1*/, 4 /*blgp: fp4 e2m1*/,
                        0, sA, 0, sB);
            }
        }
        __syncthreads();
    }

    // Epilogue (constants loaded here, once per block — keeps K-loop regs low).
    // C/D layout (16x16 shapes): col = l16 (=n), row = quad*4 + reg (=m).
    const float NEG_LOG2E = -1.4426950408889634f;
    float rowsum[2][4];
    #pragma unroll
    for (int i = 0; i < 2; ++i)
        #pragma unroll
        for (int r = 0; r < 4; ++r) rowsum[i][r] = 0.0f;

    #pragma unroll
    for (int j = 0; j < 8; ++j) {
        int ng = bn * 128 + j * 16 + l16;
        float wj  = w[ng];
        float cjl = NEG_LOG2E * constc[ng];
        #pragma unroll
        for (int i = 0; i < 2; ++i)
            #pragma unroll
            for (int r = 0; r < 4; ++r)
                rowsum[i][r] += exp2f(fmaf(acc[i][j][r], NEG_LOG2E, cjl)) * wj;
    }

    #pragma unroll
    for (int mask = 1; mask < 16; mask <<= 1)
        #pragma unroll
        for (int i = 0; i < 2; ++i)
            #pragma unroll
            for (int r = 0; r < 4; ++r)
                rowsum[i][r] += __shfl_xor(rowsum[i][r], mask, 64);

    if (l16 == 0) {
        #pragma unroll
        for (int i = 0; i < 2; ++i)
            #pragma unroll
            for (int r = 0; r < 4; ++r) {
                int mg = bm * 128 + wave_m + i * 16 + quad * 4 + r;
                atomicAdd(&score[mg], rowsum[i][r]);
            }
    }
}

// ---------------------------------------------------------------------------
// finalize: out[n] = sigmoid(score[n] + b)
// ---------------------------------------------------------------------------
__global__ void finalize(const float* __restrict__ score,
                         const float* __restrict__ b,
                         float* __restrict__ out) {
    int n = blockIdx.x * 256 + threadIdx.x;
    if (n < MDIM) {
        float s = score[n] + b[0];
        out[n] = 1.0f / (1.0f + exp2f(-1.4426950408889634f * s));
    }
}

extern "C" void kernel_launch(void* const* d_in, const int* in_sizes, int n_in,
                              void* d_out, int out_size, void* d_ws, size_t ws_size,
                              hipStream_t stream) {
    const float* x       = (const float*)d_in[0];
    const float* centers = (const float*)d_in[1];
    const float* sigmas  = (const float*)d_in[2];
    const float* w_lin   = (const float*)d_in[3];
    const float* b_lin   = (const float*)d_in[4];
    float* out = (float*)d_out;

    char* ws = (char*)d_ws;
    unsigned char* Ap = (unsigned char*)ws;                       // 4 MB
    unsigned char* Bp = (unsigned char*)(ws + (size_t)MDIM * KB); // 1 MB
    float* cc    = (float*)(ws + (size_t)MDIM * KB + (size_t)CDIM * KB); // 16 KB
    float* score = (float*)((char*)cc + CDIM * sizeof(float));    // 64 KB

    prep<<<dim3(2048 + 512), dim3(256), 0, stream>>>(
        x, centers, sigmas, Ap, Bp, cc, score);
    gemm_fused<<<dim3(CDIM / 128, MDIM / 128), dim3(256), 0, stream>>>(
        Ap, Bp, cc, w_lin, score);
    finalize<<<dim3((MDIM + 255) / 256), dim3(256), 0, stream>>>(score, b_lin, out);
}